// Round 3
// baseline (706.528 us; speedup 1.0000x reference)
//
#include <hip/hip_runtime.h>
#include <hip/hip_bf16.h>
#include <math.h>

#define D_MODEL 1024
#define D_FF    4096
#define NEXP    8
#define NTOK    4096
#define NROUTED 8192

typedef __attribute__((ext_vector_type(8))) short bf16x8;
typedef __attribute__((ext_vector_type(4))) float f32x4;
typedef __attribute__((ext_vector_type(4))) unsigned short us4;

// ---- workspace byte offsets ----
#define WS_CNT   0                         // int[8]
#define WS_CNT2  64                        // int[8]
#define WS_OFF   128                       // int[9]
#define WS_TI    256                       // int[NTOK*2]
#define WS_TW    (WS_TI + NTOK*2*4)        // float[NTOK*2]
#define WS_TOK   (WS_TW + NTOK*2*4)        // int[NROUTED]
#define WS_GWT   (WS_TOK + NROUTED*4)      // float[NROUTED]
#define WS_XG    (((WS_GWT + NROUTED*4) + 255) & ~255)       // bf16[NROUTED][1024]  (16 MB)
#define WS_H     (WS_XG + (size_t)NROUTED*D_MODEL*2)         // bf16[NROUTED][4096]  (64 MB)
#define WS_WT    (WS_H + (size_t)NROUTED*D_FF*2)             // bf16[E][F][K] shared (64 MB)
// total ~144 MB

__device__ __forceinline__ unsigned short f2bf(float f){
  union { float f; unsigned u; } a; a.f = f;
  unsigned u = a.u;
  u = u + 0x7FFF + ((u >> 16) & 1);   // RNE
  return (unsigned short)(u >> 16);
}

__device__ __forceinline__ void gload_lds16(const void* g, void* l){
  __builtin_amdgcn_global_load_lds((const __attribute__((address_space(1))) void*)g,
                                   (__attribute__((address_space(3))) void*)l, 16, 0, 0);
}

// ---------------- gating ----------------
__global__ void moe_gate_kernel(const float* __restrict__ x, const float* __restrict__ gw,
                                int* cnt, int* __restrict__ ti, float* __restrict__ tw){
  int n = blockIdx.x*4 + (threadIdx.x >> 6);
  int lane = threadIdx.x & 63;
  const float* xr = x + (size_t)n * D_MODEL;
  float acc[NEXP];
  #pragma unroll
  for (int e=0;e<NEXP;e++) acc[e] = 0.f;
  for (int d=lane; d<D_MODEL; d+=64){
    float xv = xr[d];
    #pragma unroll
    for (int e=0;e<NEXP;e++) acc[e] += xv * gw[d*NEXP + e];
  }
  #pragma unroll
  for (int e=0;e<NEXP;e++){
    #pragma unroll
    for (int o=32;o;o>>=1) acc[e] += __shfl_down(acc[e], o, 64);
  }
  if (lane == 0){
    int i0 = 0; float v0 = acc[0];
    #pragma unroll
    for (int e=1;e<NEXP;e++) if (acc[e] > v0){ v0 = acc[e]; i0 = e; }
    int i1 = -1; float v1 = -1e30f;
    #pragma unroll
    for (int e=0;e<NEXP;e++) if (e != i0 && acc[e] > v1){ v1 = acc[e]; i1 = e; }
    float p = expf(v1 - v0);
    float inv = 1.f / (1.f + p);
    ti[n*2] = i0; ti[n*2+1] = i1;
    tw[n*2] = inv; tw[n*2+1] = p * inv;
    atomicAdd(&cnt[i0], 1); atomicAdd(&cnt[i1], 1);
  }
}

__global__ void moe_prefix_kernel(const int* __restrict__ cnt, int* __restrict__ off){
  if (threadIdx.x == 0){
    int s = 0;
    for (int e=0;e<NEXP;e++){ off[e] = s; s += cnt[e]; }
    off[NEXP] = s;
  }
}

__global__ void moe_assign_kernel(const float* __restrict__ x, const int* __restrict__ ti,
                                  const float* __restrict__ tw, const int* __restrict__ off,
                                  int* cnt2, int* __restrict__ tok, float* __restrict__ gwt,
                                  unsigned short* __restrict__ Xg){
  __shared__ int ss[2];
  int n = blockIdx.x;
  if (threadIdx.x == 0){
    int i0 = ti[n*2], i1 = ti[n*2+1];
    int s0 = off[i0] + atomicAdd(&cnt2[i0], 1);
    int s1 = off[i1] + atomicAdd(&cnt2[i1], 1);
    tok[s0] = n; tok[s1] = n;
    gwt[s0] = tw[n*2]; gwt[s1] = tw[n*2+1];
    ss[0] = s0; ss[1] = s1;
  }
  __syncthreads();
  int s0 = ss[0], s1 = ss[1];
  int t = threadIdx.x;
  float4 v = ((const float4*)(x + (size_t)n * D_MODEL))[t];
  us4 pk = { f2bf(v.x), f2bf(v.y), f2bf(v.z), f2bf(v.w) };
  *(us4*)(Xg + (size_t)s0 * D_MODEL + t*4) = pk;
  *(us4*)(Xg + (size_t)s1 * D_MODEL + t*4) = pk;
}

// ---------------- weight transpose + bf16 convert: W(E,K,F) f32 -> Wt(E,F,K) bf16 ----------------
__global__ __launch_bounds__(256) void transpose_bf16_kernel(
    const float* __restrict__ W, unsigned short* __restrict__ Wt, int K, int F){
  __shared__ float tile[64][65];
  int e = blockIdx.z;
  int f0 = blockIdx.x * 64, k0 = blockIdx.y * 64;
  const float* Wb = W + (size_t)e * K * F;
  unsigned short* Wtb = Wt + (size_t)e * F * K;
  int tid = threadIdx.x;
  #pragma unroll
  for (int i=0;i<4;i++){
    int idx = i*256 + tid;
    int r = idx >> 4, c4 = (idx & 15) * 4;
    float4 v = *(const float4*)(Wb + (size_t)(k0 + r) * F + f0 + c4);
    tile[r][c4] = v.x; tile[r][c4+1] = v.y; tile[r][c4+2] = v.z; tile[r][c4+3] = v.w;
  }
  __syncthreads();
  #pragma unroll
  for (int i=0;i<4;i++){
    int idx = i*256 + tid;
    int f = idx >> 4, k4 = (idx & 15) * 4;
    us4 pk = { f2bf(tile[k4][f]), f2bf(tile[k4+1][f]), f2bf(tile[k4+2][f]), f2bf(tile[k4+3][f]) };
    *(us4*)(Wtb + (size_t)(f0 + f) * K + k0 + k4) = pk;
  }
}

// ---------------- GEMM, 2-phase double-buffered (T3-minimum) ----------------
// MODE 1: Xg@W1t^T -> gelu -> H      (KS=1)
// MODE 2: H@W2t^T *g -> atomic out   (KS=4, K split across blocks; bias added by chunk 0)
template<int MODE, int KS>
__global__ __launch_bounds__(256) void moe_gemm_kernel(
    char* __restrict__ wsb, const unsigned short* __restrict__ Bt,
    const float* __restrict__ bias, float* __restrict__ out)
{
  const int* off = (const int*)(wsb + WS_OFF);
  const int e  = blockIdx.z;
  const int n0 = off[e];
  const int ne = off[e+1] - n0;
  const int row0 = blockIdx.y * 128;
  if (row0 >= ne) return;

  const int K = (MODE==1) ? D_MODEL : D_FF;
  const int F = (MODE==1) ? D_FF    : D_MODEL;
  const int FT = F/128;                        // col tiles
  const int n_off  = (blockIdx.x % FT) * 128;
  const int kchunk = blockIdx.x / FT;
  const int kloc   = K / (64*KS);              // K-steps this block (16 for both modes)
  const int kt0    = kchunk * kloc;

  const unsigned short* Ag  = (const unsigned short*)(wsb + (MODE==1 ? (size_t)WS_XG : (size_t)WS_H));
  const unsigned short* Bgt = Bt + (size_t)e * F * K;

  __shared__ __align__(16) char As[2*16384];   // 2 x (128 rows x 64 k) bf16, src-swizzled
  __shared__ __align__(16) char Bs[2*16384];

  const int tid = threadIdx.x, lane = tid & 63, w = tid >> 6;
  const int wrow = (w>>1)*64, wcol = (w&1)*64;
  const int arow   = lane >> 3;
  const int achunk = ((lane & 7) ^ arow) << 4;

  // precompute per-lane global row base pointers for the 4 staged chunks
  const char* aptr[4]; const char* bptr[4];
  #pragma unroll
  for (int i=0;i<4;i++){
    int c = w*4 + i;
    int row = c*8 + arow;
    int gr = row0 + row; if (gr >= ne) gr = ne - 1;
    aptr[i] = (const char*)(Ag + (size_t)(n0 + gr) * K) + achunk;
    bptr[i] = (const char*)(Bgt + (size_t)(n_off + row) * K) + achunk;
  }

  f32x4 acc[4][4];
  #pragma unroll
  for (int i=0;i<4;i++)
    #pragma unroll
    for (int j=0;j<4;j++) acc[i][j] = (f32x4){0.f,0.f,0.f,0.f};

  // prologue: stage tile 0 into buf 0
  #pragma unroll
  for (int i=0;i<4;i++){
    int c = w*4 + i;
    gload_lds16(aptr[i] + kt0*128, As + c*1024);
    gload_lds16(bptr[i] + kt0*128, Bs + c*1024);
  }
  __syncthreads();

  int cur = 0;
  for (int kt = 0; kt < kloc; ++kt){
    // issue next tile's loads into the other buffer (overlaps with compute below)
    if (kt + 1 < kloc){
      int nxt = cur ^ 1;
      #pragma unroll
      for (int i=0;i<4;i++){
        int c = w*4 + i;
        gload_lds16(aptr[i] + (size_t)(kt0+kt+1)*128, As + nxt*16384 + c*1024);
        gload_lds16(bptr[i] + (size_t)(kt0+kt+1)*128, Bs + nxt*16384 + c*1024);
      }
    }
    // compute on current buffer
    const char* Ab = As + cur*16384;
    const char* Bb = Bs + cur*16384;
    #pragma unroll
    for (int kk=0; kk<2; ++kk){
      bf16x8 a[4], b[4];
      #pragma unroll
      for (int mi=0; mi<4; mi++){
        int row = wrow + mi*16 + (lane&15);
        int byteoff = (row<<7) + (((kk<<6) + ((lane>>4)<<4)) ^ ((row&7)<<4));
        a[mi] = *(const bf16x8*)(Ab + byteoff);
      }
      #pragma unroll
      for (int ni=0; ni<4; ni++){
        int col = wcol + ni*16 + (lane&15);
        int byteoff = (col<<7) + (((kk<<6) + ((lane>>4)<<4)) ^ ((col&7)<<4));
        b[ni] = *(const bf16x8*)(Bb + byteoff);
      }
      #pragma unroll
      for (int mi=0; mi<4; mi++)
        #pragma unroll
        for (int ni=0; ni<4; ni++)
          acc[mi][ni] = __builtin_amdgcn_mfma_f32_16x16x32_bf16(a[mi], b[ni], acc[mi][ni], 0, 0, 0);
    }
    // one barrier per K-step; implicit vmcnt(0)+lgkmcnt(0) drain waits for the
    // NEXT tile's stage (issued above) AFTER this tile's compute — latency hidden.
    __syncthreads();
    cur ^= 1;
  }

  // ---- epilogue ----
  if (MODE == 1){
    const float* b1 = bias + (size_t)e * D_FF;
    unsigned short* H = (unsigned short*)(wsb + (size_t)WS_H);
    #pragma unroll
    for (int mi=0; mi<4; mi++){
      int rbase = wrow + mi*16 + ((lane>>4)<<2);
      #pragma unroll
      for (int r=0;r<4;r++){
        int lrow = rbase + r;
        if (row0 + lrow < ne){
          size_t hb = (size_t)(n0 + row0 + lrow) * D_FF;
          #pragma unroll
          for (int ni=0; ni<4; ni++){
            int gcol = n_off + wcol + ni*16 + (lane&15);
            float v = acc[mi][ni][r] + b1[gcol];
            v = 0.5f * v * (1.f + erff(v * 0.70710678118654752f));
            H[hb + gcol] = f2bf(v);
          }
        }
      }
    }
  } else {
    const float* b2 = bias + (size_t)e * D_MODEL;
    const int* tok = (const int*)(wsb + WS_TOK);
    const float* gwt = (const float*)(wsb + WS_GWT);
    #pragma unroll
    for (int mi=0; mi<4; mi++){
      int rbase = wrow + mi*16 + ((lane>>4)<<2);
      #pragma unroll
      for (int r=0;r<4;r++){
        int lrow = rbase + r;
        if (row0 + lrow < ne){
          int slot = n0 + row0 + lrow;
          int tk = tok[slot];
          float g = gwt[slot];
          float* orow = out + (size_t)tk * D_MODEL;
          #pragma unroll
          for (int ni=0; ni<4; ni++){
            int gcol = n_off + wcol + ni*16 + (lane&15);
            float bb = (kchunk == 0) ? b2[gcol] : 0.f;
            atomicAdd(orow + gcol, (acc[mi][ni][r] + bb) * g);
          }
        }
      }
    }
  }
}

extern "C" void kernel_launch(void* const* d_in, const int* in_sizes, int n_in,
                              void* d_out, int out_size, void* d_ws, size_t ws_size,
                              hipStream_t stream){
  const float* x   = (const float*)d_in[0];
  const float* gw  = (const float*)d_in[1];
  const float* w1  = (const float*)d_in[2];
  const float* b1  = (const float*)d_in[3];
  const float* w2  = (const float*)d_in[4];
  const float* b2  = (const float*)d_in[5];
  float* out = (float*)d_out;
  char* ws = (char*)d_ws;
  unsigned short* Wt = (unsigned short*)(ws + (size_t)WS_WT);

  hipMemsetAsync(ws, 0, 256, stream);                                   // counters
  hipMemsetAsync(out, 0, (size_t)NTOK * D_MODEL * sizeof(float), stream);

  moe_gate_kernel<<<NTOK/4, 256, 0, stream>>>(x, gw, (int*)(ws+WS_CNT),
                                              (int*)(ws+WS_TI), (float*)(ws+WS_TW));
  moe_prefix_kernel<<<1, 64, 0, stream>>>((const int*)(ws+WS_CNT), (int*)(ws+WS_OFF));
  moe_assign_kernel<<<NTOK, 256, 0, stream>>>(x, (const int*)(ws+WS_TI),
                                              (const float*)(ws+WS_TW), (const int*)(ws+WS_OFF),
                                              (int*)(ws+WS_CNT2), (int*)(ws+WS_TOK),
                                              (float*)(ws+WS_GWT),
                                              (unsigned short*)(ws + (size_t)WS_XG));
  // W1 (E,1024,4096) f32 -> Wt (E,4096,1024) bf16 ; then GEMM1
  transpose_bf16_kernel<<<dim3(D_FF/64, D_MODEL/64, NEXP), 256, 0, stream>>>(w1, Wt, D_MODEL, D_FF);
  moe_gemm_kernel<1,1><<<dim3(D_FF/128, NTOK/128, NEXP), 256, 0, stream>>>(ws, Wt, b1, out);
  // W2 (E,4096,1024) f32 -> Wt (E,1024,4096) bf16 ; then GEMM2 (K split 4-way)
  transpose_bf16_kernel<<<dim3(D_MODEL/64, D_FF/64, NEXP), 256, 0, stream>>>(w2, Wt, D_FF, D_MODEL);
  moe_gemm_kernel<2,4><<<dim3((D_MODEL/128)*4, NTOK/128, NEXP), 256, 0, stream>>>(ws, Wt, b2, out);
}

// Round 4
// 659.262 us; speedup vs baseline: 1.0717x; 1.0717x over previous
//
#include <hip/hip_runtime.h>
#include <hip/hip_bf16.h>
#include <math.h>

#define D_MODEL 1024
#define D_FF    4096
#define NEXP    8
#define NTOK    4096
#define NROUTED 8192

typedef __attribute__((ext_vector_type(8))) short bf16x8;
typedef __attribute__((ext_vector_type(4))) float f32x4;
typedef __attribute__((ext_vector_type(4))) unsigned short us4;

// ---- workspace byte offsets ----
#define WS_CNT   0                         // int[8]
#define WS_CNT2  64                        // int[8]
#define WS_OFF   128                       // int[9]
#define WS_TI    256                       // int[NTOK*2]
#define WS_TW    (WS_TI + NTOK*2*4)        // float[NTOK*2]
#define WS_TOK   (WS_TW + NTOK*2*4)        // int[NROUTED]
#define WS_GWT   (WS_TOK + NROUTED*4)      // float[NROUTED]
#define WS_XG    (((WS_GWT + NROUTED*4) + 255) & ~255)       // bf16[NROUTED][1024]  (16 MB)
#define WS_H     (WS_XG + (size_t)NROUTED*D_MODEL*2)         // bf16[NROUTED][4096]  (64 MB)
#define WS_WT    (WS_H + (size_t)NROUTED*D_FF*2)             // bf16[E][F][K] shared (64 MB)
// total ~144 MB

__device__ __forceinline__ unsigned short f2bf(float f){
  union { float f; unsigned u; } a; a.f = f;
  unsigned u = a.u;
  u = u + 0x7FFF + ((u >> 16) & 1);   // RNE
  return (unsigned short)(u >> 16);
}

__device__ __forceinline__ void gload_lds16(const void* g, void* l){
  __builtin_amdgcn_global_load_lds((const __attribute__((address_space(1))) void*)g,
                                   (__attribute__((address_space(3))) void*)l, 16, 0, 0);
}

// ---------------- gating ----------------
__global__ void moe_gate_kernel(const float* __restrict__ x, const float* __restrict__ gw,
                                int* cnt, int* __restrict__ ti, float* __restrict__ tw){
  int n = blockIdx.x*4 + (threadIdx.x >> 6);
  int lane = threadIdx.x & 63;
  const float* xr = x + (size_t)n * D_MODEL;
  float acc[NEXP];
  #pragma unroll
  for (int e=0;e<NEXP;e++) acc[e] = 0.f;
  for (int d=lane; d<D_MODEL; d+=64){
    float xv = xr[d];
    #pragma unroll
    for (int e=0;e<NEXP;e++) acc[e] += xv * gw[d*NEXP + e];
  }
  #pragma unroll
  for (int e=0;e<NEXP;e++){
    #pragma unroll
    for (int o=32;o;o>>=1) acc[e] += __shfl_down(acc[e], o, 64);
  }
  if (lane == 0){
    int i0 = 0; float v0 = acc[0];
    #pragma unroll
    for (int e=1;e<NEXP;e++) if (acc[e] > v0){ v0 = acc[e]; i0 = e; }
    int i1 = -1; float v1 = -1e30f;
    #pragma unroll
    for (int e=0;e<NEXP;e++) if (e != i0 && acc[e] > v1){ v1 = acc[e]; i1 = e; }
    float p = expf(v1 - v0);
    float inv = 1.f / (1.f + p);
    ti[n*2] = i0; ti[n*2+1] = i1;
    tw[n*2] = inv; tw[n*2+1] = p * inv;
    atomicAdd(&cnt[i0], 1); atomicAdd(&cnt[i1], 1);
  }
}

__global__ void moe_prefix_kernel(const int* __restrict__ cnt, int* __restrict__ off){
  if (threadIdx.x == 0){
    int s = 0;
    for (int e=0;e<NEXP;e++){ off[e] = s; s += cnt[e]; }
    off[NEXP] = s;
  }
}

__global__ void moe_assign_kernel(const float* __restrict__ x, const int* __restrict__ ti,
                                  const float* __restrict__ tw, const int* __restrict__ off,
                                  int* cnt2, int* __restrict__ tok, float* __restrict__ gwt,
                                  unsigned short* __restrict__ Xg){
  __shared__ int ss[2];
  int n = blockIdx.x;
  if (threadIdx.x == 0){
    int i0 = ti[n*2], i1 = ti[n*2+1];
    int s0 = off[i0] + atomicAdd(&cnt2[i0], 1);
    int s1 = off[i1] + atomicAdd(&cnt2[i1], 1);
    tok[s0] = n; tok[s1] = n;
    gwt[s0] = tw[n*2]; gwt[s1] = tw[n*2+1];
    ss[0] = s0; ss[1] = s1;
  }
  __syncthreads();
  int s0 = ss[0], s1 = ss[1];
  int t = threadIdx.x;
  float4 v = ((const float4*)(x + (size_t)n * D_MODEL))[t];
  us4 pk = { f2bf(v.x), f2bf(v.y), f2bf(v.z), f2bf(v.w) };
  *(us4*)(Xg + (size_t)s0 * D_MODEL + t*4) = pk;
  *(us4*)(Xg + (size_t)s1 * D_MODEL + t*4) = pk;
}

// ---------------- weight transpose + bf16 convert: W(E,K,F) f32 -> Wt(E,F,K) bf16 ----------------
__global__ __launch_bounds__(256) void transpose_bf16_kernel(
    const float* __restrict__ W, unsigned short* __restrict__ Wt, int K, int F){
  __shared__ float tile[64][65];
  int e = blockIdx.z;
  int f0 = blockIdx.x * 64, k0 = blockIdx.y * 64;
  const float* Wb = W + (size_t)e * K * F;
  unsigned short* Wtb = Wt + (size_t)e * F * K;
  int tid = threadIdx.x;
  #pragma unroll
  for (int i=0;i<4;i++){
    int idx = i*256 + tid;
    int r = idx >> 4, c4 = (idx & 15) * 4;
    float4 v = *(const float4*)(Wb + (size_t)(k0 + r) * F + f0 + c4);
    tile[r][c4] = v.x; tile[r][c4+1] = v.y; tile[r][c4+2] = v.z; tile[r][c4+3] = v.w;
  }
  __syncthreads();
  #pragma unroll
  for (int i=0;i<4;i++){
    int idx = i*256 + tid;
    int f = idx >> 4, k4 = (idx & 15) * 4;
    us4 pk = { f2bf(tile[k4][f]), f2bf(tile[k4+1][f]), f2bf(tile[k4+2][f]), f2bf(tile[k4+3][f]) };
    *(us4*)(Wtb + (size_t)(f0 + f) * K + k0 + k4) = pk;
  }
}

// ---------------- GEMM: 256x256 tile, BK=32, 8 waves, 3-buffer LDS ring, counted vmcnt ----------------
// MODE 1: Xg@W1t^T -> gelu -> H      (KS=1, K=1024, 32 K-tiles)
// MODE 2: H@W2t^T *g -> atomic out   (KS=4, K-chunk=1024, 32 K-tiles; bias by chunk 0)
// LDS per buf: A[256][32] bf16 (16KB) + B[256][32] bf16 (16KB); 3 bufs = 96KB.
// Swizzle: 16B chunk q at row r holds global chunk q ^ ((r>>1)&3)  (2-way bank = free).
template<int MODE, int KS>
__global__ __launch_bounds__(512, 1) void moe_gemm_kernel(
    char* __restrict__ wsb, const unsigned short* __restrict__ Bt,
    const float* __restrict__ bias, float* __restrict__ out)
{
  const int* off = (const int*)(wsb + WS_OFF);

  const int K  = (MODE==1) ? D_MODEL : D_FF;
  const int F  = (MODE==1) ? D_FF    : D_MODEL;
  const int FT = F/256;
  const int gx = FT*KS, gy = NROUTED/256;      // both GEMMs: gx=16, gy=32, gz=8 -> nwg=4096
  // XCD-chunked bijective swizzle (nwg % 8 == 0)
  int f = ((int)blockIdx.z*gy + (int)blockIdx.y)*gx + (int)blockIdx.x;
  f = (f & 7)*(gx*gy*NEXP/8) + (f >> 3);
  const int bx = f % gx, by = (f / gx) % gy, e = f / (gx*gy);

  const int n0 = off[e];
  const int ne = off[e+1] - n0;
  const int row0 = by * 256;
  if (row0 >= ne) return;

  const int n_off  = (bx % FT) * 256;
  const int kchunk = bx / FT;
  const int nt     = K / (32*KS);              // 32 K-tiles per block
  const int ktb0   = kchunk * nt * 64;         // byte offset of K-chunk within a row

  const unsigned short* Ag  = (const unsigned short*)(wsb + (MODE==1 ? (size_t)WS_XG : (size_t)WS_H));
  const unsigned short* Bgt = Bt + (size_t)e * F * K;
  const size_t K2 = (size_t)K * 2;

  __shared__ __align__(16) char lds[3*32768];

  const int tid = threadIdx.x, lane = tid & 63, w = tid >> 6;
  const int wr = w >> 2, wc = w & 3;           // 2 x 4 wave grid; wave output 128 x 64

  // ---- staging source pointers (pre-swizzled: dest (row,p) gets global chunk p^f(row)) ----
  const int srow = tid >> 2;                   // 0..127  (instr i adds +128)
  const int fq   = (srow >> 1) & 3;            // f(row) == f(row+128)
  const int qsB  = ((tid & 3) ^ fq) << 4;      // source byte chunk
  int ra0 = row0 + srow;        if (ra0 >= ne) ra0 = ne - 1;
  int ra1 = row0 + 128 + srow;  if (ra1 >= ne) ra1 = ne - 1;
  const char* aSrc0 = (const char*)(Ag + (size_t)(n0 + ra0) * K) + ktb0 + qsB;
  const char* aSrc1 = (const char*)(Ag + (size_t)(n0 + ra1) * K) + ktb0 + qsB;
  const char* bSrc0 = (const char*)(Bgt + (size_t)(n_off + srow) * K) + ktb0 + qsB;
  const char* bSrc1 = (const char*)(Bgt + (size_t)(n_off + 128 + srow) * K) + ktb0 + qsB;
  const int dstOff = w * 1024;                 // wave-uniform LDS dest base offset

  // ---- fragment LDS read offsets (fixed per lane; buffer base varies) ----
  const int q0 = lane >> 4;
  int aoff[8], boff[4];
  #pragma unroll
  for (int mi=0; mi<8; mi++){
    int row = wr*128 + mi*16 + (lane & 15);
    aoff[mi] = row*64 + ((q0 ^ ((row>>1)&3)) << 4);
  }
  #pragma unroll
  for (int ni=0; ni<4; ni++){
    int col = wc*64 + ni*16 + (lane & 15);
    boff[ni] = 16384 + col*64 + ((q0 ^ ((col>>1)&3)) << 4);
  }

  f32x4 acc[8][4];
  #pragma unroll
  for (int i=0;i<8;i++)
    #pragma unroll
    for (int j=0;j<4;j++) acc[i][j] = (f32x4){0.f,0.f,0.f,0.f};

  #define STAGE(tt, bb) { \
    size_t kb = (size_t)(tt) * 64; \
    char* dA = lds + (bb)*32768 + dstOff; \
    gload_lds16(aSrc0 + kb, dA); \
    gload_lds16(aSrc1 + kb, dA + 8192); \
    gload_lds16(bSrc0 + kb, dA + 16384); \
    gload_lds16(bSrc1 + kb, dA + 24576); }

  // prologue: 2 K-tiles in flight (8 loads/thread outstanding)
  STAGE(0, 0);
  STAGE(1, 1);

  for (int t = 0; t < nt; ++t){
    // wait own loads of tile t (newest 4 outstanding = tile t+1); cross-wave via barrier
    if (t < nt-1) asm volatile("s_waitcnt vmcnt(4)" ::: "memory");
    else          asm volatile("s_waitcnt vmcnt(0)" ::: "memory");
    __builtin_amdgcn_s_barrier();
    __builtin_amdgcn_sched_barrier(0);

    if (t + 2 < nt) STAGE(t + 2, (t + 2) % 3);   // prefetch 2 ahead (ring slot is free: last read at tile t-1)

    const char* buf = lds + (t % 3) * 32768;
    bf16x8 af[8], bf[4];
    #pragma unroll
    for (int mi=0; mi<8; mi++) af[mi] = *(const bf16x8*)(buf + aoff[mi]);
    #pragma unroll
    for (int ni=0; ni<4; ni++) bf[ni] = *(const bf16x8*)(buf + boff[ni]);

    asm volatile("s_waitcnt lgkmcnt(0)" ::: "memory");
    __builtin_amdgcn_sched_barrier(0);
    __builtin_amdgcn_s_setprio(1);
    #pragma unroll
    for (int ni=0; ni<4; ni++)
      #pragma unroll
      for (int mi=0; mi<8; mi++)
        acc[mi][ni] = __builtin_amdgcn_mfma_f32_16x16x32_bf16(af[mi], bf[ni], acc[mi][ni], 0, 0, 0);
    __builtin_amdgcn_s_setprio(0);
    __builtin_amdgcn_sched_barrier(0);
    __builtin_amdgcn_s_barrier();
  }
  #undef STAGE

  // ---- epilogue ----
  if (MODE == 1){
    const float* b1 = bias + (size_t)e * D_FF;
    unsigned short* H = (unsigned short*)(wsb + (size_t)WS_H);
    #pragma unroll
    for (int mi=0; mi<8; mi++){
      int rbase = wr*128 + mi*16 + ((lane>>4)<<2);
      #pragma unroll
      for (int r=0;r<4;r++){
        int lrow = rbase + r;
        if (row0 + lrow < ne){
          size_t hb = (size_t)(n0 + row0 + lrow) * D_FF;
          #pragma unroll
          for (int ni=0; ni<4; ni++){
            int gcol = n_off + wc*64 + ni*16 + (lane&15);
            float v = acc[mi][ni][r] + b1[gcol];
            v = 0.5f * v * (1.f + erff(v * 0.70710678118654752f));
            H[hb + gcol] = f2bf(v);
          }
        }
      }
    }
  } else {
    const float* b2 = bias + (size_t)e * D_MODEL;
    const int* tok = (const int*)(wsb + WS_TOK);
    const float* gwt = (const float*)(wsb + WS_GWT);
    #pragma unroll
    for (int mi=0; mi<8; mi++){
      int rbase = wr*128 + mi*16 + ((lane>>4)<<2);
      #pragma unroll
      for (int r=0;r<4;r++){
        int lrow = rbase + r;
        if (row0 + lrow < ne){
          int slot = n0 + row0 + lrow;
          int tk = tok[slot];
          float g = gwt[slot];
          float* orow = out + (size_t)tk * D_MODEL;
          #pragma unroll
          for (int ni=0; ni<4; ni++){
            int gcol = n_off + wc*64 + ni*16 + (lane&15);
            float bb = (kchunk == 0) ? b2[gcol] : 0.f;
            atomicAdd(orow + gcol, (acc[mi][ni][r] + bb) * g);
          }
        }
      }
    }
  }
}

extern "C" void kernel_launch(void* const* d_in, const int* in_sizes, int n_in,
                              void* d_out, int out_size, void* d_ws, size_t ws_size,
                              hipStream_t stream){
  const float* x   = (const float*)d_in[0];
  const float* gw  = (const float*)d_in[1];
  const float* w1  = (const float*)d_in[2];
  const float* b1  = (const float*)d_in[3];
  const float* w2  = (const float*)d_in[4];
  const float* b2  = (const float*)d_in[5];
  float* out = (float*)d_out;
  char* ws = (char*)d_ws;
  unsigned short* Wt = (unsigned short*)(ws + (size_t)WS_WT);

  hipMemsetAsync(ws, 0, 256, stream);                                   // counters
  hipMemsetAsync(out, 0, (size_t)NTOK * D_MODEL * sizeof(float), stream);

  moe_gate_kernel<<<NTOK/4, 256, 0, stream>>>(x, gw, (int*)(ws+WS_CNT),
                                              (int*)(ws+WS_TI), (float*)(ws+WS_TW));
  moe_prefix_kernel<<<1, 64, 0, stream>>>((const int*)(ws+WS_CNT), (int*)(ws+WS_OFF));
  moe_assign_kernel<<<NTOK, 256, 0, stream>>>(x, (const int*)(ws+WS_TI),
                                              (const float*)(ws+WS_TW), (const int*)(ws+WS_OFF),
                                              (int*)(ws+WS_CNT2), (int*)(ws+WS_TOK),
                                              (float*)(ws+WS_GWT),
                                              (unsigned short*)(ws + (size_t)WS_XG));
  // W1 (E,1024,4096) f32 -> Wt (E,4096,1024) bf16 ; then GEMM1
  transpose_bf16_kernel<<<dim3(D_FF/64, D_MODEL/64, NEXP), 256, 0, stream>>>(w1, Wt, D_MODEL, D_FF);
  moe_gemm_kernel<1,1><<<dim3(16, NROUTED/256, NEXP), 512, 0, stream>>>(ws, Wt, b1, out);
  // W2 (E,4096,1024) f32 -> Wt (E,1024,4096) bf16 ; then GEMM2 (K split 4-way)
  transpose_bf16_kernel<<<dim3(D_MODEL/64, D_FF/64, NEXP), 256, 0, stream>>>(w2, Wt, D_FF, D_MODEL);
  moe_gemm_kernel<2,4><<<dim3(16, NROUTED/256, NEXP), 512, 0, stream>>>(ws, Wt, b2, out);
}